// Round 2
// baseline (317.122 us; speedup 1.0000x reference)
//
#include <hip/hip_runtime.h>

#define N_NODES   50000
#define N_EDGES   800000
#define IN_DIM    100
#define HIDDEN    16
#define N_CLASSES 40

// Bucketing geometry
#define BSHIFT 7
#define NPB    128                       // nodes per bucket (1 << BSHIFT)
#define NBKT   391                       // ceil(N_NODES / NPB)
#define PB     256                       // partition blocks
#define EPB    3125                      // edges per partition block (exact: 256*3125=800000)
#define HSZ    (NBKT * PB)               // 100096 (bucket-major: H[k*PB + b])
#define HPAD   102400                    // 1024 threads * 100 entries (scan coverage)

// ---------------------------------------------------------------------------
// y1 = X @ W1   [N,100] @ [100,16] -> [N,16]
// ---------------------------------------------------------------------------
#define GROWS 64
__global__ __launch_bounds__(256) void gemm_xw1(const float* __restrict__ X,
                                                const float* __restrict__ W,
                                                float* __restrict__ Y) {
    __shared__ __align__(16) float sX[GROWS * IN_DIM];   // 25.6 KB
    __shared__ __align__(16) float sW[IN_DIM * HIDDEN];  // 6.4 KB
    const int tid  = threadIdx.x;
    const int row0 = blockIdx.x * GROWS;
    const int nrows = min(GROWS, N_NODES - row0);

    const float4* W4 = (const float4*)W;
    float4* sW4 = (float4*)sW;
    for (int i = tid; i < (IN_DIM * HIDDEN) / 4; i += 256) sW4[i] = W4[i];

    const float4* X4 = (const float4*)(X + (size_t)row0 * IN_DIM);
    float4* sX4 = (float4*)sX;
    const int nf4 = nrows * (IN_DIM / 4);
    for (int i = tid; i < nf4; i += 256) sX4[i] = X4[i];
    __syncthreads();

    const int r = tid >> 2;   // 0..63
    const int q = tid & 3;    // output quad
    if (r >= nrows) return;

    float4 acc = make_float4(0.f, 0.f, 0.f, 0.f);
    const float* xr = &sX[r * IN_DIM];
#pragma unroll
    for (int k = 0; k < IN_DIM; ++k) {
        const float xk = xr[k];
        const float4 w = *(const float4*)&sW[k * HIDDEN + q * 4];
        acc.x = fmaf(xk, w.x, acc.x);
        acc.y = fmaf(xk, w.y, acc.y);
        acc.z = fmaf(xk, w.z, acc.z);
        acc.w = fmaf(xk, w.w, acc.w);
    }
    *(float4*)&Y[(size_t)(row0 + r) * HIDDEN + q * 4] = acc;
}

// ---------------------------------------------------------------------------
// Pass 1: per-block LDS bucket histogram -> H[k*PB + b]  (no global atomics)
// ---------------------------------------------------------------------------
__global__ __launch_bounds__(256) void hist_kernel(const int* __restrict__ dst,
                                                   int* __restrict__ H) {
    __shared__ int cnt[NBKT];
    const int tid = threadIdx.x, b = blockIdx.x;
    for (int k = tid; k < NBKT; k += 256) cnt[k] = 0;
    __syncthreads();
    const int e0 = b * EPB;
    for (int i = tid; i < EPB; i += 256)
        atomicAdd(&cnt[dst[e0 + i] >> BSHIFT], 1);
    __syncthreads();
    for (int k = tid; k < NBKT; k += 256) H[k * PB + b] = cnt[k];
    if (b == 0)  // zero the scan pad so garbage can't enter valid prefixes
        for (int i = HSZ + tid; i < HPAD; i += 256) H[i] = 0;
}

// ---------------------------------------------------------------------------
// Pass 2: in-place exclusive scan of H[0..HPAD) — one block, 1024 threads,
// 100 entries (25 int4) per thread; sums re-read from L2 (no big reg arrays).
// ---------------------------------------------------------------------------
__global__ __launch_bounds__(1024) void scan_kernel(int* __restrict__ H) {
    const int t = threadIdx.x;
    const int4* H4 = (const int4*)H;
    int s = 0;
#pragma unroll
    for (int i = 0; i < 25; ++i) {
        const int4 v = H4[t * 25 + i];
        s += v.x + v.y + v.z + v.w;
    }
    __shared__ int sd[1024];
    sd[t] = s;
    __syncthreads();
    for (int off = 1; off < 1024; off <<= 1) {
        const int v = (t >= off) ? sd[t - off] : 0;
        __syncthreads();
        sd[t] += v;
        __syncthreads();
    }
    int run = sd[t] - s;  // exclusive prefix of this thread's chunk
#pragma unroll
    for (int i = 0; i < 25; ++i) {
        const int4 v = H4[t * 25 + i];
        int4 w;
        w.x = run; run += v.x;
        w.y = run; run += v.y;
        w.z = run; run += v.z;
        w.w = run; run += v.w;
        ((int4*)H)[t * 25 + i] = w;
    }
}

// ---------------------------------------------------------------------------
// Pass 3: partition. Each block ranks its edges with LDS atomics and writes
// each (bucket,block) run contiguously -> no cross-XCD line sharing.
// Payload: {src(16b) | dst_low(7b)<<16, val}.
// ---------------------------------------------------------------------------
__global__ __launch_bounds__(512) void partition_kernel(const int* __restrict__ src,
                                                        const int* __restrict__ dst,
                                                        const float* __restrict__ val,
                                                        const int* __restrict__ Hbase,
                                                        int2* __restrict__ binned) {
    __shared__ int cur[NBKT];
    const int tid = threadIdx.x, b = blockIdx.x;
    for (int k = tid; k < NBKT; k += 512) cur[k] = Hbase[k * PB + b];
    __syncthreads();
    const int e0 = b * EPB;
    for (int i = tid; i < EPB; i += 512) {
        const int e = e0 + i;
        const int d = dst[e];
        const int s = src[e];
        const float v = val[e];
        const int k = d >> BSHIFT;
        const int pos = atomicAdd(&cur[k], 1);
        binned[pos] = make_int2(s | ((d & (NPB - 1)) << 16), __float_as_int(v));
    }
}

// ---------------------------------------------------------------------------
// SpMM: one block per bucket; 128x16 f32 accumulator in LDS (ds_add_f32).
// 16 lanes per edge (lane = hidden dim); output tile written once, coalesced.
// ---------------------------------------------------------------------------
template <bool RELU_OUT>
__global__ __launch_bounds__(512) void spmm_bucket(const int* __restrict__ Hbase,
                                                   const int2* __restrict__ binned,
                                                   const float* __restrict__ X,
                                                   float* __restrict__ Z) {
    __shared__ float acc[NPB * HIDDEN];  // 8 KB
    const int tid = threadIdx.x, k = blockIdx.x;
    for (int i = tid; i < NPB * HIDDEN; i += 512) acc[i] = 0.f;
    const int beg = Hbase[k * PB];
    const int end = (k == NBKT - 1) ? N_EDGES : Hbase[(k + 1) * PB];
    __syncthreads();

    const int j = tid & 15;
    int p = beg + (tid >> 4);
    for (; p + 32 < end; p += 64) {  // 2-way MLP
        const int2 e0 = binned[p];
        const int2 e1 = binned[p + 32];
        const float x0 = X[(size_t)(e0.x & 0xFFFF) * HIDDEN + j];
        const float x1 = X[(size_t)(e1.x & 0xFFFF) * HIDDEN + j];
        atomicAdd(&acc[(e0.x >> 16) * HIDDEN + j], __int_as_float(e0.y) * x0);
        atomicAdd(&acc[(e1.x >> 16) * HIDDEN + j], __int_as_float(e1.y) * x1);
    }
    if (p < end) {
        const int2 e0 = binned[p];
        const float x0 = X[(size_t)(e0.x & 0xFFFF) * HIDDEN + j];
        atomicAdd(&acc[(e0.x >> 16) * HIDDEN + j], __int_as_float(e0.y) * x0);
    }
    __syncthreads();

    const int node = k * NPB + (tid >> 2);           // 4 threads per node
    if (node < N_NODES) {
        float4 o = *(const float4*)&acc[tid * 4];
        if (RELU_OUT) {
            o.x = fmaxf(o.x, 0.f); o.y = fmaxf(o.y, 0.f);
            o.z = fmaxf(o.z, 0.f); o.w = fmaxf(o.w, 0.f);
        }
        *(float4*)&Z[(size_t)node * HIDDEN + (tid & 3) * 4] = o;
    }
}

// ---------------------------------------------------------------------------
// out[n] = log_softmax(Z[n] @ W2)
// ---------------------------------------------------------------------------
__global__ __launch_bounds__(64) void out_logsoftmax(const float* __restrict__ Z,
                                                     const float* __restrict__ W2,
                                                     float* __restrict__ out) {
    __shared__ __align__(16) float sW[HIDDEN * N_CLASSES];  // 2.56 KB
    const int tid = threadIdx.x;
    const float4* W4 = (const float4*)W2;
    float4* sW4 = (float4*)sW;
    for (int i = tid; i < (HIDDEN * N_CLASSES) / 4; i += 64) sW4[i] = W4[i];
    __syncthreads();

    const int n = blockIdx.x * 64 + tid;
    if (n >= N_NODES) return;

    float z[HIDDEN];
    const float4* zp = (const float4*)(Z + (size_t)n * HIDDEN);
#pragma unroll
    for (int qz = 0; qz < 4; ++qz) {
        const float4 t = zp[qz];
        z[qz * 4 + 0] = t.x; z[qz * 4 + 1] = t.y;
        z[qz * 4 + 2] = t.z; z[qz * 4 + 3] = t.w;
    }

    float o[N_CLASSES];
#pragma unroll
    for (int c4 = 0; c4 < N_CLASSES / 4; ++c4) {
        float4 a = make_float4(0.f, 0.f, 0.f, 0.f);
#pragma unroll
        for (int kk = 0; kk < HIDDEN; ++kk) {
            const float4 w = *(const float4*)&sW[kk * N_CLASSES + c4 * 4];
            a.x = fmaf(z[kk], w.x, a.x);
            a.y = fmaf(z[kk], w.y, a.y);
            a.z = fmaf(z[kk], w.z, a.z);
            a.w = fmaf(z[kk], w.w, a.w);
        }
        o[c4 * 4 + 0] = a.x; o[c4 * 4 + 1] = a.y;
        o[c4 * 4 + 2] = a.z; o[c4 * 4 + 3] = a.w;
    }

    float m = -INFINITY;
#pragma unroll
    for (int c = 0; c < N_CLASSES; ++c) m = fmaxf(m, o[c]);
    float s = 0.f;
#pragma unroll
    for (int c = 0; c < N_CLASSES; ++c) s += __expf(o[c] - m);
    const float lse = m + __logf(s);

    float4* op4 = (float4*)(out + (size_t)n * N_CLASSES);
#pragma unroll
    for (int c4 = 0; c4 < N_CLASSES / 4; ++c4)
        op4[c4] = make_float4(o[c4 * 4 + 0] - lse, o[c4 * 4 + 1] - lse,
                              o[c4 * 4 + 2] - lse, o[c4 * 4 + 3] - lse);
}

extern "C" void kernel_launch(void* const* d_in, const int* in_sizes, int n_in,
                              void* d_out, int out_size, void* d_ws, size_t ws_size,
                              hipStream_t stream) {
    const float* features = (const float*)d_in[0];  // [50000,100]
    const int*   edge_src = (const int*)d_in[1];    // [800000]
    const int*   edge_dst = (const int*)d_in[2];    // [800000]
    const float* edge_val = (const float*)d_in[3];  // [800000]
    const float* W1       = (const float*)d_in[4];  // [100,16]
    const float* W2       = (const float*)d_in[5];  // [16,40]
    float*       out      = (float*)d_out;          // [50000,40]

    char* base = (char*)d_ws;
    const size_t HNB = (size_t)N_NODES * HIDDEN * sizeof(float);     // 3.2 MB
    float* y1     = (float*)(base);                                  // reused as z2
    float* z1     = (float*)(base + HNB);
    int*   H      = (int*)  (base + 2 * HNB);                        // 102400 ints
    int2*  binned = (int2*) (base + 2 * HNB + 512 * 1024);           // 6.4 MB
    float* z2     = y1;

    // CSR-lite build (bucket-partitioned, no global data atomics, no memsets)
    hist_kernel<<<PB, 256, 0, stream>>>(edge_dst, H);
    scan_kernel<<<1, 1024, 0, stream>>>(H);
    partition_kernel<<<PB, 512, 0, stream>>>(edge_src, edge_dst, edge_val, H, binned);

    // dense pipeline
    gemm_xw1<<<(N_NODES + GROWS - 1) / GROWS, 256, 0, stream>>>(features, W1, y1);

    // z1 = relu(A @ y1)
    spmm_bucket<true><<<NBKT, 512, 0, stream>>>(H, binned, y1, z1);

    // z2 = A @ z1
    spmm_bucket<false><<<NBKT, 512, 0, stream>>>(H, binned, z1, z2);

    // out = log_softmax(z2 @ W2)
    out_logsoftmax<<<(N_NODES + 63) / 64, 64, 0, stream>>>(z2, W2, out);
}

// Round 3
// 155.641 us; speedup vs baseline: 2.0375x; 2.0375x over previous
//
#include <hip/hip_runtime.h>

#define N_NODES   50000
#define N_EDGES   800000
#define IN_DIM    100
#define HIDDEN    16
#define N_CLASSES 40

// Bucketing geometry: bucket = dst >> 6 (64 nodes per bucket)
#define BSHIFT 6
#define NPB    64                        // nodes per bucket
#define NBKT   782                       // ceil(N_NODES / NPB)
#define PB     256                       // partition blocks
#define EPB    3125                      // edges per partition block (256*3125 = 800000)

// ---------------------------------------------------------------------------
// y1 = X @ W1   [N,100] @ [100,16] -> [N,16]
// ---------------------------------------------------------------------------
#define GROWS 64
__global__ __launch_bounds__(256) void gemm_xw1(const float* __restrict__ X,
                                                const float* __restrict__ W,
                                                float* __restrict__ Y) {
    __shared__ __align__(16) float sX[GROWS * IN_DIM];   // 25.6 KB
    __shared__ __align__(16) float sW[IN_DIM * HIDDEN];  // 6.4 KB
    const int tid  = threadIdx.x;
    const int row0 = blockIdx.x * GROWS;
    const int nrows = min(GROWS, N_NODES - row0);

    const float4* W4 = (const float4*)W;
    float4* sW4 = (float4*)sW;
    for (int i = tid; i < (IN_DIM * HIDDEN) / 4; i += 256) sW4[i] = W4[i];

    const float4* X4 = (const float4*)(X + (size_t)row0 * IN_DIM);
    float4* sX4 = (float4*)sX;
    const int nf4 = nrows * (IN_DIM / 4);
    for (int i = tid; i < nf4; i += 256) sX4[i] = X4[i];
    __syncthreads();

    const int r = tid >> 2;   // 0..63
    const int q = tid & 3;    // output quad
    if (r >= nrows) return;

    float4 acc = make_float4(0.f, 0.f, 0.f, 0.f);
    const float* xr = &sX[r * IN_DIM];
#pragma unroll
    for (int k = 0; k < IN_DIM; ++k) {
        const float xk = xr[k];
        const float4 w = *(const float4*)&sW[k * HIDDEN + q * 4];
        acc.x = fmaf(xk, w.x, acc.x);
        acc.y = fmaf(xk, w.y, acc.y);
        acc.z = fmaf(xk, w.z, acc.z);
        acc.w = fmaf(xk, w.w, acc.w);
    }
    *(float4*)&Y[(size_t)(row0 + r) * HIDDEN + q * 4] = acc;
}

// ---------------------------------------------------------------------------
// Pass 1: bucket totals. Per-block LDS int histogram, then one global int
// atomicAdd per (block,bucket) -- ~200k atomics total.
// ---------------------------------------------------------------------------
__global__ __launch_bounds__(256) void hist_kernel(const int* __restrict__ dst,
                                                   int* __restrict__ bktCnt) {
    __shared__ int cnt[NBKT];
    const int tid = threadIdx.x, b = blockIdx.x;
    for (int k = tid; k < NBKT; k += 256) cnt[k] = 0;
    __syncthreads();
    const int e0 = b * EPB;
    for (int i = tid; i < EPB; i += 256)
        atomicAdd(&cnt[dst[e0 + i] >> BSHIFT], 1);
    __syncthreads();
    for (int k = tid; k < NBKT; k += 256) {
        const int c = cnt[k];
        if (c) atomicAdd(&bktCnt[k], c);
    }
}

// ---------------------------------------------------------------------------
// Pass 2: exclusive scan of 782 bucket totals (one block). Writes bktOff and
// initializes the reservation cursors.
// ---------------------------------------------------------------------------
__global__ __launch_bounds__(1024) void scan_kernel(const int* __restrict__ bktCnt,
                                                    int* __restrict__ bktOff,
                                                    int* __restrict__ cursor) {
    __shared__ int sd[1024];
    const int t = threadIdx.x;
    const int v = (t < NBKT) ? bktCnt[t] : 0;
    sd[t] = v;
    __syncthreads();
    for (int off = 1; off < 1024; off <<= 1) {
        const int u = (t >= off) ? sd[t - off] : 0;
        __syncthreads();
        sd[t] += u;
        __syncthreads();
    }
    const int excl = sd[t] - v;
    if (t <= NBKT) bktOff[t] = excl;   // t == NBKT -> N_EDGES
    if (t < NBKT)  cursor[t] = excl;
}

// ---------------------------------------------------------------------------
// Pass 3: partition into buckets. Per-block LDS histogram -> one global
// reservation atomic per (block,bucket) -> rank-scatter. Each (block,bucket)
// run is contiguous, so no cross-XCD 64B-line sharing.
// Payload: {src | dst_low6 << 16, val}.
// ---------------------------------------------------------------------------
__global__ __launch_bounds__(512) void partition_kernel(const int* __restrict__ src,
                                                        const int* __restrict__ dst,
                                                        const float* __restrict__ val,
                                                        int* __restrict__ cursor,
                                                        int2* __restrict__ binned) {
    __shared__ int cnt[NBKT];
    const int tid = threadIdx.x, b = blockIdx.x;
    for (int k = tid; k < NBKT; k += 512) cnt[k] = 0;
    __syncthreads();
    const int e0 = b * EPB;
    for (int i = tid; i < EPB; i += 512)
        atomicAdd(&cnt[dst[e0 + i] >> BSHIFT], 1);
    __syncthreads();
    for (int k = tid; k < NBKT; k += 512) {
        const int c = cnt[k];
        cnt[k] = c ? atomicAdd(&cursor[k], c) : 0;   // cnt[k] becomes running pos
    }
    __syncthreads();
    for (int i = tid; i < EPB; i += 512) {
        const int e = e0 + i;
        const int d = dst[e];
        const int k = d >> BSHIFT;
        const int pos = atomicAdd(&cnt[k], 1);
        binned[pos] = make_int2(src[e] | ((d & (NPB - 1)) << 16),
                                __float_as_int(val[e]));
    }
}

// ---------------------------------------------------------------------------
// Pass 4: per-bucket counting sort by node -> node-sorted edge list + CSR offs.
// All LDS atomics are int (native ds_add_u32); writes land in a block-local
// 8 KB window of `sorted`.
// ---------------------------------------------------------------------------
__global__ __launch_bounds__(256) void sort_kernel(const int* __restrict__ bktOff,
                                                   const int2* __restrict__ binned,
                                                   int2* __restrict__ sorted,
                                                   int* __restrict__ offs) {
    __shared__ int cnt[NPB];
    __shared__ int cur[NPB];
    const int tid = threadIdx.x, k = blockIdx.x;
    if (tid < NPB) cnt[tid] = 0;
    const int beg = bktOff[k];
    const int end = bktOff[k + 1];
    __syncthreads();
    for (int p = beg + tid; p < end; p += 256)
        atomicAdd(&cnt[(binned[p].x >> 16) & (NPB - 1)], 1);
    __syncthreads();
    if (tid < NPB) {           // one wave: shfl exclusive scan of 64 counts
        const int v = cnt[tid];
        int x = v;
#pragma unroll
        for (int d = 1; d < 64; d <<= 1) {
            const int y = __shfl_up(x, d, 64);
            if (tid >= d) x += y;
        }
        const int excl = x - v;
        cur[tid] = beg + excl;
        const int node = k * NPB + tid;
        if (node < N_NODES) offs[node] = beg + excl;
    }
    if (k == NBKT - 1 && tid == 0) offs[N_NODES] = N_EDGES;
    __syncthreads();
    for (int p = beg + tid; p < end; p += 256) {
        const int2 e = binned[p];
        const int pos = atomicAdd(&cur[(e.x >> 16) & (NPB - 1)], 1);
        sorted[pos] = make_int2(e.x & 0xFFFF, e.y);
    }
}

// ---------------------------------------------------------------------------
// Atomic-free CSR gather SpMM: 16 lanes own one node, register accumulate.
// 3125 blocks x 256 threads, tiny VGPR -> ~full occupancy for latency hiding.
// ---------------------------------------------------------------------------
template <bool RELU_OUT>
__global__ __launch_bounds__(256) void gather_spmm(const int* __restrict__ offs,
                                                   const int2* __restrict__ sorted,
                                                   const float* __restrict__ X,
                                                   float* __restrict__ Z) {
    const int tid = threadIdx.x;
    const int n = blockIdx.x * 16 + (tid >> 4);   // grid exact: 50000/16
    const int j = tid & 15;
    const int beg = offs[n];
    const int end = offs[n + 1];

    float acc = 0.f;
    int p = beg;
    for (; p + 4 <= end; p += 4) {                 // 4 independent loads in flight
        const int2 e0 = sorted[p];
        const int2 e1 = sorted[p + 1];
        const int2 e2 = sorted[p + 2];
        const int2 e3 = sorted[p + 3];
        const float x0 = X[(size_t)e0.x * HIDDEN + j];
        const float x1 = X[(size_t)e1.x * HIDDEN + j];
        const float x2 = X[(size_t)e2.x * HIDDEN + j];
        const float x3 = X[(size_t)e3.x * HIDDEN + j];
        acc = fmaf(__int_as_float(e0.y), x0, acc);
        acc = fmaf(__int_as_float(e1.y), x1, acc);
        acc = fmaf(__int_as_float(e2.y), x2, acc);
        acc = fmaf(__int_as_float(e3.y), x3, acc);
    }
    for (; p < end; ++p) {
        const int2 e = sorted[p];
        acc = fmaf(__int_as_float(e.y), X[(size_t)e.x * HIDDEN + j], acc);
    }
    if (RELU_OUT) acc = fmaxf(acc, 0.f);
    Z[(size_t)n * HIDDEN + j] = acc;
}

// ---------------------------------------------------------------------------
// out[n] = log_softmax(Z[n] @ W2)
// ---------------------------------------------------------------------------
__global__ __launch_bounds__(64) void out_logsoftmax(const float* __restrict__ Z,
                                                     const float* __restrict__ W2,
                                                     float* __restrict__ out) {
    __shared__ __align__(16) float sW[HIDDEN * N_CLASSES];  // 2.56 KB
    const int tid = threadIdx.x;
    const float4* W4 = (const float4*)W2;
    float4* sW4 = (float4*)sW;
    for (int i = tid; i < (HIDDEN * N_CLASSES) / 4; i += 64) sW4[i] = W4[i];
    __syncthreads();

    const int n = blockIdx.x * 64 + tid;
    if (n >= N_NODES) return;

    float z[HIDDEN];
    const float4* zp = (const float4*)(Z + (size_t)n * HIDDEN);
#pragma unroll
    for (int qz = 0; qz < 4; ++qz) {
        const float4 t = zp[qz];
        z[qz * 4 + 0] = t.x; z[qz * 4 + 1] = t.y;
        z[qz * 4 + 2] = t.z; z[qz * 4 + 3] = t.w;
    }

    float o[N_CLASSES];
#pragma unroll
    for (int c4 = 0; c4 < N_CLASSES / 4; ++c4) {
        float4 a = make_float4(0.f, 0.f, 0.f, 0.f);
#pragma unroll
        for (int kk = 0; kk < HIDDEN; ++kk) {
            const float4 w = *(const float4*)&sW[kk * N_CLASSES + c4 * 4];
            a.x = fmaf(z[kk], w.x, a.x);
            a.y = fmaf(z[kk], w.y, a.y);
            a.z = fmaf(z[kk], w.z, a.z);
            a.w = fmaf(z[kk], w.w, a.w);
        }
        o[c4 * 4 + 0] = a.x; o[c4 * 4 + 1] = a.y;
        o[c4 * 4 + 2] = a.z; o[c4 * 4 + 3] = a.w;
    }

    float m = -INFINITY;
#pragma unroll
    for (int c = 0; c < N_CLASSES; ++c) m = fmaxf(m, o[c]);
    float s = 0.f;
#pragma unroll
    for (int c = 0; c < N_CLASSES; ++c) s += __expf(o[c] - m);
    const float lse = m + __logf(s);

    float4* op4 = (float4*)(out + (size_t)n * N_CLASSES);
#pragma unroll
    for (int c4 = 0; c4 < N_CLASSES / 4; ++c4)
        op4[c4] = make_float4(o[c4 * 4 + 0] - lse, o[c4 * 4 + 1] - lse,
                              o[c4 * 4 + 2] - lse, o[c4 * 4 + 3] - lse);
}

extern "C" void kernel_launch(void* const* d_in, const int* in_sizes, int n_in,
                              void* d_out, int out_size, void* d_ws, size_t ws_size,
                              hipStream_t stream) {
    const float* features = (const float*)d_in[0];  // [50000,100]
    const int*   edge_src = (const int*)d_in[1];    // [800000]
    const int*   edge_dst = (const int*)d_in[2];    // [800000]
    const float* edge_val = (const float*)d_in[3];  // [800000]
    const float* W1       = (const float*)d_in[4];  // [100,16]
    const float* W2       = (const float*)d_in[5];  // [16,40]
    float*       out      = (float*)d_out;          // [50000,40]

    char* base = (char*)d_ws;
    const size_t HNB = (size_t)N_NODES * HIDDEN * sizeof(float);   // 3.2 MB
    float* y1     = (float*)(base);                                // reused as z2
    float* z1     = (float*)(base + HNB);
    int2*  binned = (int2*) (base + 2 * HNB);                      // 6.4 MB
    int2*  sorted = (int2*) (base + 2 * HNB + (size_t)N_EDGES * 8);// 6.4 MB
    char*  meta   = base + 2 * HNB + 2 * (size_t)N_EDGES * 8;
    int*   bktCnt = (int*)(meta);                                  // 782 ints
    int*   bktOff = (int*)(meta + 4096);                           // 783 ints
    int*   cursor = (int*)(meta + 8192);                           // 782 ints
    int*   offs   = (int*)(meta + 12288);                          // 50001 ints
    float* z2     = y1;

    // --- CSR build: hist -> scan(782) -> partition -> per-bucket sort ---
    hipMemsetAsync(bktCnt, 0, NBKT * sizeof(int), stream);
    hist_kernel<<<PB, 256, 0, stream>>>(edge_dst, bktCnt);
    scan_kernel<<<1, 1024, 0, stream>>>(bktCnt, bktOff, cursor);
    partition_kernel<<<PB, 512, 0, stream>>>(edge_src, edge_dst, edge_val,
                                             cursor, binned);
    sort_kernel<<<NBKT, 256, 0, stream>>>(bktOff, binned, sorted, offs);

    // --- dense pipeline ---
    gemm_xw1<<<(N_NODES + GROWS - 1) / GROWS, 256, 0, stream>>>(features, W1, y1);

    // z1 = relu(A @ y1)
    gather_spmm<true><<<N_NODES / 16, 256, 0, stream>>>(offs, sorted, y1, z1);

    // z2 = A @ z1
    gather_spmm<false><<<N_NODES / 16, 256, 0, stream>>>(offs, sorted, z1, z2);

    // out = log_softmax(z2 @ W2)
    out_logsoftmax<<<(N_NODES + 63) / 64, 64, 0, stream>>>(z2, W2, out);
}

// Round 4
// 140.940 us; speedup vs baseline: 2.2501x; 1.1043x over previous
//
#include <hip/hip_runtime.h>

#define N_NODES   50000
#define N_EDGES   800000
#define IN_DIM    100
#define HIDDEN    16
#define N_CLASSES 40

// Bucketing geometry: bucket = dst >> 6 (64 nodes per bucket)
#define BSHIFT 6
#define NPB    64                        // nodes per bucket
#define NBKT   782                       // ceil(N_NODES / NPB)
#define PB     256                       // partition blocks
#define EPB    3125                      // edges per partition block (256*3125 = 800000)
#define BTW    (NBKT + 1)                // BT row width (783)
#define CAP    2048                      // padded per-bucket capacity in `sorted`
                                         // (bucket size ~ Binom(800k, 64/50k): mean 1024, sd 32 -> 2048 = +32 sd)

// ---------------------------------------------------------------------------
// y1 = X @ W1   [N,100] @ [100,16] -> [N,16]
// ---------------------------------------------------------------------------
#define GROWS 64
__global__ __launch_bounds__(256) void gemm_xw1(const float* __restrict__ X,
                                                const float* __restrict__ W,
                                                float* __restrict__ Y) {
    __shared__ __align__(16) float sX[GROWS * IN_DIM];   // 25.6 KB
    __shared__ __align__(16) float sW[IN_DIM * HIDDEN];  // 6.4 KB
    const int tid  = threadIdx.x;
    const int row0 = blockIdx.x * GROWS;
    const int nrows = min(GROWS, N_NODES - row0);

    const float4* W4 = (const float4*)W;
    float4* sW4 = (float4*)sW;
    for (int i = tid; i < (IN_DIM * HIDDEN) / 4; i += 256) sW4[i] = W4[i];

    const float4* X4 = (const float4*)(X + (size_t)row0 * IN_DIM);
    float4* sX4 = (float4*)sX;
    const int nf4 = nrows * (IN_DIM / 4);
    for (int i = tid; i < nf4; i += 256) sX4[i] = X4[i];
    __syncthreads();

    const int r = tid >> 2;   // 0..63
    const int q = tid & 3;    // output quad
    if (r >= nrows) return;

    float4 acc = make_float4(0.f, 0.f, 0.f, 0.f);
    const float* xr = &sX[r * IN_DIM];
#pragma unroll
    for (int k = 0; k < IN_DIM; ++k) {
        const float xk = xr[k];
        const float4 w = *(const float4*)&sW[k * HIDDEN + q * 4];
        acc.x = fmaf(xk, w.x, acc.x);
        acc.y = fmaf(xk, w.y, acc.y);
        acc.z = fmaf(xk, w.z, acc.z);
        acc.w = fmaf(xk, w.w, acc.w);
    }
    *(float4*)&Y[(size_t)(row0 + r) * HIDDEN + q * 4] = acc;
}

// ---------------------------------------------------------------------------
// Pass 1: partition. Block b owns binned[b*EPB .. (b+1)*EPB): LDS histogram ->
// LDS scan -> LDS-stage edges grouped by bucket -> LINEAR coalesced copy-out.
// No global atomics, no reservation, no separate hist/scan kernels.
// BT[b*BTW + k] = local start of bucket k's run inside the block's region.
// Payload: {src | dst_low6 << 16, val}.
// ---------------------------------------------------------------------------
__global__ __launch_bounds__(512) void partition_kernel(const int* __restrict__ src,
                                                        const int* __restrict__ dst,
                                                        const float* __restrict__ val,
                                                        int* __restrict__ BT,
                                                        int2* __restrict__ binned) {
    __shared__ int  cnt[NBKT];        // 3.1 KB
    __shared__ int  lcur[NBKT];       // 3.1 KB
    __shared__ int  sd[512];          // 2 KB
    __shared__ int2 staged[EPB];      // 25 KB

    const int tid = threadIdx.x, b = blockIdx.x;
    const int e0 = b * EPB;

    for (int k = tid; k < NBKT; k += 512) cnt[k] = 0;
    __syncthreads();
    for (int i = tid; i < EPB; i += 512)
        atomicAdd(&cnt[dst[e0 + i] >> BSHIFT], 1);
    __syncthreads();

    // block-wide exclusive scan over 782 buckets (2 per thread)
    const int k0 = 2 * tid, k1 = 2 * tid + 1;
    const int a  = (k0 < NBKT) ? cnt[k0] : 0;
    const int bb = (k1 < NBKT) ? cnt[k1] : 0;
    const int s  = a + bb;
    sd[tid] = s;
    __syncthreads();
    for (int off = 1; off < 512; off <<= 1) {
        const int u = (tid >= off) ? sd[tid - off] : 0;
        __syncthreads();
        sd[tid] += u;
        __syncthreads();
    }
    const int excl = sd[tid] - s;
    if (k0 < NBKT) { lcur[k0] = excl;     BT[b * BTW + k0] = excl; }
    if (k1 < NBKT) { lcur[k1] = excl + a; BT[b * BTW + k1] = excl + a; }
    if (tid == 0)  BT[b * BTW + NBKT] = EPB;
    __syncthreads();

    // LDS-stage edges ordered by bucket (re-read edges: L2-hot, same XCD)
    for (int i = tid; i < EPB; i += 512) {
        const int e = e0 + i;
        const int d = dst[e];
        const int k = d >> BSHIFT;
        const int pos = atomicAdd(&lcur[k], 1);
        staged[pos] = make_int2(src[e] | ((d & (NPB - 1)) << 16),
                                __float_as_int(val[e]));
    }
    __syncthreads();

    // linear coalesced copy-out
    for (int i = tid; i < EPB; i += 512)
        binned[e0 + i] = staged[i];
}

// ---------------------------------------------------------------------------
// Pass 2: per-bucket node sort. Block k gathers its 256 runs (one per thread,
// located via BT), counts per node, wave-scans, ranks into LDS staging, then
// LINEAR coalesced copy-out into padded sorted[k*CAP ..]. meta[n]={beg,deg}.
// ---------------------------------------------------------------------------
__global__ __launch_bounds__(256) void sort_kernel(const int* __restrict__ BT,
                                                   const int2* __restrict__ binned,
                                                   int2* __restrict__ sorted,
                                                   int2* __restrict__ meta) {
    __shared__ int  cnt[NPB];
    __shared__ int  cur[NPB];
    __shared__ int  sTot;
    __shared__ int2 staged[CAP];      // 16 KB

    const int tid = threadIdx.x, k = blockIdx.x;
    if (tid < NPB) cnt[tid] = 0;
    __syncthreads();

    // each thread owns partition-block t's run for bucket k
    const int rs = BT[tid * BTW + k];
    const int re = BT[tid * BTW + k + 1];
    const int2* rb = binned + (size_t)tid * EPB;

    for (int p = rs; p < re; ++p)
        atomicAdd(&cnt[(rb[p].x >> 16) & (NPB - 1)], 1);
    __syncthreads();

    if (tid < NPB) {  // one wave: shfl exclusive scan of 64 counts
        const int v = cnt[tid];
        int x = v;
#pragma unroll
        for (int d = 1; d < 64; d <<= 1) {
            const int y = __shfl_up(x, d, 64);
            if (tid >= d) x += y;
        }
        const int excl = x - v;
        cur[tid] = excl;
        const int node = k * NPB + tid;
        if (node < N_NODES) meta[node] = make_int2(k * CAP + excl, v);
        if (tid == NPB - 1) sTot = x;
    }
    __syncthreads();

    for (int p = rs; p < re; ++p) {   // rank into LDS (reads L2-hot)
        const int2 e = rb[p];
        const int  n = (e.x >> 16) & (NPB - 1);
        const int pos = atomicAdd(&cur[n], 1);
        staged[pos] = make_int2(e.x & 0xFFFF, e.y);
    }
    __syncthreads();

    const int m = sTot;
    for (int i = tid; i < m; i += 256)
        sorted[(size_t)k * CAP + i] = staged[i];
}

// ---------------------------------------------------------------------------
// z1 = relu(A @ y1): atomic-free gather, 16 lanes per node, register accum.
// ---------------------------------------------------------------------------
__global__ __launch_bounds__(256) void gather_relu(const int2* __restrict__ meta,
                                                   const int2* __restrict__ sorted,
                                                   const float* __restrict__ X,
                                                   float* __restrict__ Z) {
    const int tid = threadIdx.x;
    const int n = blockIdx.x * 16 + (tid >> 4);   // grid exact: 50000/16
    const int j = tid & 15;
    const int2 md = meta[n];
    const int beg = md.x, end = md.x + md.y;

    float acc = 0.f;
    int p = beg;
    for (; p + 4 <= end; p += 4) {
        const int2 e0 = sorted[p];
        const int2 e1 = sorted[p + 1];
        const int2 e2 = sorted[p + 2];
        const int2 e3 = sorted[p + 3];
        const float x0 = X[(size_t)e0.x * HIDDEN + j];
        const float x1 = X[(size_t)e1.x * HIDDEN + j];
        const float x2 = X[(size_t)e2.x * HIDDEN + j];
        const float x3 = X[(size_t)e3.x * HIDDEN + j];
        acc = fmaf(__int_as_float(e0.y), x0, acc);
        acc = fmaf(__int_as_float(e1.y), x1, acc);
        acc = fmaf(__int_as_float(e2.y), x2, acc);
        acc = fmaf(__int_as_float(e3.y), x3, acc);
    }
    for (; p < end; ++p) {
        const int2 e = sorted[p];
        acc = fmaf(__int_as_float(e.y), X[(size_t)e.x * HIDDEN + j], acc);
    }
    Z[(size_t)n * HIDDEN + j] = fmaxf(acc, 0.f);
}

// ---------------------------------------------------------------------------
// Fused: z2 = A @ z1 (register gather) -> LDS transpose -> out = lsm(z2 @ W2).
// 16 lanes/node; lane j owns classes {j, j+16, j+32(j<8)}; shfl_xor(16) reduce.
// ---------------------------------------------------------------------------
__global__ __launch_bounds__(256) void gather_out(const int2* __restrict__ meta,
                                                  const int2* __restrict__ sorted,
                                                  const float* __restrict__ X,
                                                  const float* __restrict__ W2,
                                                  float* __restrict__ out) {
    __shared__ float sW[688];          // 640 used; padded so k*40+j+32 reads stay in-bounds
    __shared__ float zt[16 * HIDDEN];  // 1 KB transpose tile
    const int tid = threadIdx.x;
    for (int i = tid; i < HIDDEN * N_CLASSES; i += 256) sW[i] = W2[i];

    const int g = tid >> 4;            // node-in-block
    const int j = tid & 15;
    const int n = blockIdx.x * 16 + g; // grid exact: 50000/16

    const int2 md = meta[n];
    const int beg = md.x, end = md.x + md.y;
    float acc = 0.f;
    int p = beg;
    for (; p + 4 <= end; p += 4) {
        const int2 e0 = sorted[p];
        const int2 e1 = sorted[p + 1];
        const int2 e2 = sorted[p + 2];
        const int2 e3 = sorted[p + 3];
        const float x0 = X[(size_t)e0.x * HIDDEN + j];
        const float x1 = X[(size_t)e1.x * HIDDEN + j];
        const float x2 = X[(size_t)e2.x * HIDDEN + j];
        const float x3 = X[(size_t)e3.x * HIDDEN + j];
        acc = fmaf(__int_as_float(e0.y), x0, acc);
        acc = fmaf(__int_as_float(e1.y), x1, acc);
        acc = fmaf(__int_as_float(e2.y), x2, acc);
        acc = fmaf(__int_as_float(e3.y), x3, acc);
    }
    for (; p < end; ++p) {
        const int2 e = sorted[p];
        acc = fmaf(__int_as_float(e.y), X[(size_t)e.x * HIDDEN + j], acc);
    }
    zt[g * HIDDEN + j] = acc;
    __syncthreads();

    // lane j: classes j, j+16, and j+32 when j < 8
    float o0 = 0.f, o1 = 0.f, o2 = 0.f;
    const float* zr = &zt[g * HIDDEN];
#pragma unroll
    for (int k = 0; k < HIDDEN; ++k) {
        const float zk = zr[k];
        o0 = fmaf(zk, sW[k * N_CLASSES + j], o0);
        o1 = fmaf(zk, sW[k * N_CLASSES + j + 16], o1);
        o2 = fmaf(zk, sW[k * N_CLASSES + j + 32], o2);  // garbage for j>=8, masked below
    }
    const bool has3 = (j < 8);
    float m = fmaxf(o0, o1);
    if (has3) m = fmaxf(m, o2);
#pragma unroll
    for (int d = 1; d < 16; d <<= 1) m = fmaxf(m, __shfl_xor(m, d, 16));
    float se = __expf(o0 - m) + __expf(o1 - m);
    if (has3) se += __expf(o2 - m);
#pragma unroll
    for (int d = 1; d < 16; d <<= 1) se += __shfl_xor(se, d, 16);
    const float lse = m + __logf(se);

    float* orow = out + (size_t)n * N_CLASSES;
    orow[j]      = o0 - lse;
    orow[j + 16] = o1 - lse;
    if (has3) orow[j + 32] = o2 - lse;
}

extern "C" void kernel_launch(void* const* d_in, const int* in_sizes, int n_in,
                              void* d_out, int out_size, void* d_ws, size_t ws_size,
                              hipStream_t stream) {
    const float* features = (const float*)d_in[0];  // [50000,100]
    const int*   edge_src = (const int*)d_in[1];    // [800000]
    const int*   edge_dst = (const int*)d_in[2];    // [800000]
    const float* edge_val = (const float*)d_in[3];  // [800000]
    const float* W1       = (const float*)d_in[4];  // [100,16]
    const float* W2       = (const float*)d_in[5];  // [16,40]
    float*       out      = (float*)d_out;          // [50000,40]

    char* base = (char*)d_ws;
    const size_t HNB = (size_t)N_NODES * HIDDEN * sizeof(float);       // 3.2 MB
    float* y1     = (float*)(base);
    float* z1     = (float*)(base + HNB);
    int2*  binned = (int2*) (base + 2 * HNB);                          // 6.4 MB
    int2*  sortd  = (int2*) (base + 2 * HNB + (size_t)N_EDGES * 8);    // 12.8 MB (782*2048*8)
    char*  tail   = base + 2 * HNB + (size_t)N_EDGES * 8
                         + (size_t)NBKT * CAP * 8;
    int*   BT     = (int*) (tail);                                     // 256*783*4 = 802 KB
    int2*  meta   = (int2*)(tail + ((size_t)PB * BTW * 4 + 255 & ~255ULL)); // 400 KB

    // --- build: 2 dispatches, all writes coalesced, zero global atomics ---
    partition_kernel<<<PB, 512, 0, stream>>>(edge_src, edge_dst, edge_val, BT, binned);
    sort_kernel<<<NBKT, 256, 0, stream>>>(BT, binned, sortd, meta);

    // --- dense pipeline: 3 dispatches ---
    gemm_xw1<<<(N_NODES + GROWS - 1) / GROWS, 256, 0, stream>>>(features, W1, y1);
    gather_relu<<<N_NODES / 16, 256, 0, stream>>>(meta, sortd, y1, z1);
    gather_out<<<N_NODES / 16, 256, 0, stream>>>(meta, sortd, z1, W2, out);
}

// Round 5
// 139.053 us; speedup vs baseline: 2.2806x; 1.0136x over previous
//
#include <hip/hip_runtime.h>

#define N_NODES   50000
#define N_EDGES   800000
#define IN_DIM    100
#define HIDDEN    16
#define N_CLASSES 40

// Bucketing geometry: bucket = dst >> 6 (64 nodes per bucket)
#define BSHIFT 6
#define NPB    64                        // nodes per bucket
#define NBKT   782                       // ceil(N_NODES / NPB)
#define PB     256                       // partition blocks
#define EPB    3125                      // edges per partition block (256*3125 = 800000)
#define CAP    2048                      // padded per-bucket capacity in `sorted`
#define GNODES 32                        // nodes per gather block (8 lanes/node, 256 thr)

// ---------------------------------------------------------------------------
// y1 = X @ W1   [N,100] @ [100,16] -> [N,16]
// ---------------------------------------------------------------------------
#define GROWS 64
__global__ __launch_bounds__(256) void gemm_xw1(const float* __restrict__ X,
                                                const float* __restrict__ W,
                                                float* __restrict__ Y) {
    __shared__ __align__(16) float sX[GROWS * IN_DIM];   // 25.6 KB
    __shared__ __align__(16) float sW[IN_DIM * HIDDEN];  // 6.4 KB
    const int tid  = threadIdx.x;
    const int row0 = blockIdx.x * GROWS;
    const int nrows = min(GROWS, N_NODES - row0);

    const float4* W4 = (const float4*)W;
    float4* sW4 = (float4*)sW;
    for (int i = tid; i < (IN_DIM * HIDDEN) / 4; i += 256) sW4[i] = W4[i];

    const float4* X4 = (const float4*)(X + (size_t)row0 * IN_DIM);
    float4* sX4 = (float4*)sX;
    const int nf4 = nrows * (IN_DIM / 4);
    for (int i = tid; i < nf4; i += 256) sX4[i] = X4[i];
    __syncthreads();

    const int r = tid >> 2;   // 0..63
    const int q = tid & 3;    // output quad
    if (r >= nrows) return;

    float4 acc = make_float4(0.f, 0.f, 0.f, 0.f);
    const float* xr = &sX[r * IN_DIM];
#pragma unroll
    for (int k = 0; k < IN_DIM; ++k) {
        const float xk = xr[k];
        const float4 w = *(const float4*)&sW[k * HIDDEN + q * 4];
        acc.x = fmaf(xk, w.x, acc.x);
        acc.y = fmaf(xk, w.y, acc.y);
        acc.z = fmaf(xk, w.z, acc.z);
        acc.w = fmaf(xk, w.w, acc.w);
    }
    *(float4*)&Y[(size_t)(row0 + r) * HIDDEN + q * 4] = acc;
}

// ---------------------------------------------------------------------------
// Pass 1: partition. Block b owns binned[b*EPB .. (b+1)*EPB): LDS histogram ->
// LDS scan -> LDS-stage edges grouped by bucket -> LINEAR coalesced copy-out.
// BTt is TRANSPOSED: BTt[k*PB + b] = local start of bucket k's run in block b.
// (Transposed so sort_kernel's boundary reads are coalesced.)
// Payload: {src | dst_low6 << 16, val}.
// ---------------------------------------------------------------------------
__global__ __launch_bounds__(512) void partition_kernel(const int* __restrict__ src,
                                                        const int* __restrict__ dst,
                                                        const float* __restrict__ val,
                                                        int* __restrict__ BTt,
                                                        int2* __restrict__ binned) {
    __shared__ int  cnt[NBKT];        // 3.1 KB
    __shared__ int  lcur[NBKT];       // 3.1 KB
    __shared__ int  sd[512];          // 2 KB
    __shared__ int2 staged[EPB];      // 25 KB

    const int tid = threadIdx.x, b = blockIdx.x;
    const int e0 = b * EPB;

    for (int k = tid; k < NBKT; k += 512) cnt[k] = 0;
    __syncthreads();
    for (int i = tid; i < EPB; i += 512)
        atomicAdd(&cnt[dst[e0 + i] >> BSHIFT], 1);
    __syncthreads();

    // block-wide exclusive scan over 782 buckets (2 per thread)
    const int k0 = 2 * tid, k1 = 2 * tid + 1;
    const int a  = (k0 < NBKT) ? cnt[k0] : 0;
    const int bb = (k1 < NBKT) ? cnt[k1] : 0;
    const int s  = a + bb;
    sd[tid] = s;
    __syncthreads();
    for (int off = 1; off < 512; off <<= 1) {
        const int u = (tid >= off) ? sd[tid - off] : 0;
        __syncthreads();
        sd[tid] += u;
        __syncthreads();
    }
    const int excl = sd[tid] - s;
    if (k0 < NBKT) { lcur[k0] = excl;     BTt[k0 * PB + b] = excl; }
    if (k1 < NBKT) { lcur[k1] = excl + a; BTt[k1 * PB + b] = excl + a; }
    if (tid == 0)  BTt[NBKT * PB + b] = EPB;
    __syncthreads();

    // LDS-stage edges ordered by bucket (re-read edges: L2-hot)
    for (int i = tid; i < EPB; i += 512) {
        const int e = e0 + i;
        const int d = dst[e];
        const int k = d >> BSHIFT;
        const int pos = atomicAdd(&lcur[k], 1);
        staged[pos] = make_int2(src[e] | ((d & (NPB - 1)) << 16),
                                __float_as_int(val[e]));
    }
    __syncthreads();

    // linear coalesced copy-out
    for (int i = tid; i < EPB; i += 512)
        binned[e0 + i] = staged[i];
}

// ---------------------------------------------------------------------------
// Pass 2: per-bucket node sort. Block k reads its 256 run boundaries from the
// transposed BTt (COALESCED), counts per node, wave-scans with each segment
// start padded to EVEN index (16B alignment for int4 edge-pair loads), ranks
// into LDS staging, linear coalesced copy-out. meta[n] = {beg, deg}.
// ---------------------------------------------------------------------------
__global__ __launch_bounds__(256) void sort_kernel(const int* __restrict__ BTt,
                                                   const int2* __restrict__ binned,
                                                   int2* __restrict__ sorted,
                                                   int2* __restrict__ meta) {
    __shared__ int  cnt[NPB];
    __shared__ int  cur[NPB];
    __shared__ int  sTot;
    __shared__ int2 staged[CAP];      // 16 KB

    const int tid = threadIdx.x, k = blockIdx.x;
    if (tid < NPB) cnt[tid] = 0;
    __syncthreads();

    // thread t owns partition-block t's run for bucket k (coalesced reads)
    const int rs = BTt[k * PB + tid];
    const int re = BTt[(k + 1) * PB + tid];
    const int2* rb = binned + (size_t)tid * EPB;

    for (int p = rs; p < re; ++p)
        atomicAdd(&cnt[(rb[p].x >> 16) & (NPB - 1)], 1);
    __syncthreads();

    if (tid < NPB) {  // one wave: shfl exclusive scan of padded counts
        const int v  = cnt[tid];
        const int vp = (v + 1) & ~1;          // even-pad -> 16B-aligned segments
        int x = vp;
#pragma unroll
        for (int d = 1; d < 64; d <<= 1) {
            const int y = __shfl_up(x, d, 64);
            if (tid >= d) x += y;
        }
        const int excl = x - vp;
        cur[tid] = excl;
        const int node = k * NPB + tid;
        if (node < N_NODES) meta[node] = make_int2(k * CAP + excl, v);
        if (tid == NPB - 1) sTot = x;
    }
    __syncthreads();

    for (int p = rs; p < re; ++p) {   // rank into LDS
        const int2 e = rb[p];
        const int  n = (e.x >> 16) & (NPB - 1);
        const int pos = atomicAdd(&cur[n], 1);
        staged[pos] = make_int2(e.x & 0xFFFF, e.y);
    }
    __syncthreads();

    const int m = sTot;
    for (int i = tid; i < m; i += 256)
        sorted[(size_t)k * CAP + i] = staged[i];
}

// ---------------------------------------------------------------------------
// Atomic-free gather SpMM: 8 lanes per node (lane j owns float2 of the row),
// edges consumed as int4 pairs (2 edges / 16B broadcast load).
// ---------------------------------------------------------------------------
template <bool RELU_OUT>
__global__ __launch_bounds__(256) void gather_spmm(const int2* __restrict__ meta,
                                                   const int2* __restrict__ sorted,
                                                   const float* __restrict__ X,
                                                   float* __restrict__ Z) {
    const int tid = threadIdx.x;
    const int g = tid >> 3, j = tid & 7;
    const int n = blockIdx.x * GNODES + g;
    if (n >= N_NODES) return;
    const int2 md = meta[n];
    const int beg = md.x, end = md.x + md.y;
    const float2* X2 = (const float2*)X;

    float2 acc = make_float2(0.f, 0.f);
    int p = beg;                                   // even -> 16B aligned
    for (; p + 4 <= end; p += 4) {
        const int4 ea = *(const int4*)&sorted[p];      // edges p, p+1
        const int4 eb = *(const int4*)&sorted[p + 2];  // edges p+2, p+3
        const float2 x0 = X2[(size_t)ea.x * 8 + j];
        const float2 x1 = X2[(size_t)ea.z * 8 + j];
        const float2 x2 = X2[(size_t)eb.x * 8 + j];
        const float2 x3 = X2[(size_t)eb.z * 8 + j];
        const float v0 = __int_as_float(ea.y), v1 = __int_as_float(ea.w);
        const float v2 = __int_as_float(eb.y), v3 = __int_as_float(eb.w);
        acc.x = fmaf(v0, x0.x, acc.x); acc.y = fmaf(v0, x0.y, acc.y);
        acc.x = fmaf(v1, x1.x, acc.x); acc.y = fmaf(v1, x1.y, acc.y);
        acc.x = fmaf(v2, x2.x, acc.x); acc.y = fmaf(v2, x2.y, acc.y);
        acc.x = fmaf(v3, x3.x, acc.x); acc.y = fmaf(v3, x3.y, acc.y);
    }
    for (; p < end; ++p) {
        const int2 e = sorted[p];
        const float2 x = X2[(size_t)e.x * 8 + j];
        const float v = __int_as_float(e.y);
        acc.x = fmaf(v, x.x, acc.x); acc.y = fmaf(v, x.y, acc.y);
    }
    if (RELU_OUT) { acc.x = fmaxf(acc.x, 0.f); acc.y = fmaxf(acc.y, 0.f); }
    ((float2*)Z)[(size_t)n * 8 + j] = acc;         // 8 lanes x 8B = 64B / node
}

// ---------------------------------------------------------------------------
// Fused: z2 = A @ z1 (8-lane register gather) -> padded LDS transpose ->
// out = log_softmax(z2 @ W2). Lane j owns classes [5j, 5j+5); width-8 shfl.
// ---------------------------------------------------------------------------
__global__ __launch_bounds__(256) void gather_out(const int2* __restrict__ meta,
                                                  const int2* __restrict__ sorted,
                                                  const float* __restrict__ X,
                                                  const float* __restrict__ W2,
                                                  float* __restrict__ out) {
    __shared__ float sW[HIDDEN * N_CLASSES];   // 2.56 KB
    __shared__ float zt[GNODES * 17];          // +1 pad: conflict-free transpose
    const int tid = threadIdx.x;
    for (int i = tid; i < HIDDEN * N_CLASSES; i += 256) sW[i] = W2[i];

    const int g = tid >> 3, j = tid & 7;
    const int n = blockIdx.x * GNODES + g;

    float2 acc = make_float2(0.f, 0.f);
    if (n < N_NODES) {
        const int2 md = meta[n];
        const int beg = md.x, end = md.x + md.y;
        const float2* X2 = (const float2*)X;
        int p = beg;
        for (; p + 4 <= end; p += 4) {
            const int4 ea = *(const int4*)&sorted[p];
            const int4 eb = *(const int4*)&sorted[p + 2];
            const float2 x0 = X2[(size_t)ea.x * 8 + j];
            const float2 x1 = X2[(size_t)ea.z * 8 + j];
            const float2 x2 = X2[(size_t)eb.x * 8 + j];
            const float2 x3 = X2[(size_t)eb.z * 8 + j];
            const float v0 = __int_as_float(ea.y), v1 = __int_as_float(ea.w);
            const float v2 = __int_as_float(eb.y), v3 = __int_as_float(eb.w);
            acc.x = fmaf(v0, x0.x, acc.x); acc.y = fmaf(v0, x0.y, acc.y);
            acc.x = fmaf(v1, x1.x, acc.x); acc.y = fmaf(v1, x1.y, acc.y);
            acc.x = fmaf(v2, x2.x, acc.x); acc.y = fmaf(v2, x2.y, acc.y);
            acc.x = fmaf(v3, x3.x, acc.x); acc.y = fmaf(v3, x3.y, acc.y);
        }
        for (; p < end; ++p) {
            const int2 e = sorted[p];
            const float2 x = X2[(size_t)e.x * 8 + j];
            const float v = __int_as_float(e.y);
            acc.x = fmaf(v, x.x, acc.x); acc.y = fmaf(v, x.y, acc.y);
        }
    }
    zt[g * 17 + j * 2]     = acc.x;
    zt[g * 17 + j * 2 + 1] = acc.y;
    __syncthreads();
    if (n >= N_NODES) return;

    float z[HIDDEN];
#pragma unroll
    for (int k = 0; k < HIDDEN; ++k) z[k] = zt[g * 17 + k];

    float o[5];
#pragma unroll
    for (int i = 0; i < 5; ++i) o[i] = 0.f;
#pragma unroll
    for (int k = 0; k < HIDDEN; ++k) {
        const float zk = z[k];
#pragma unroll
        for (int i = 0; i < 5; ++i)
            o[i] = fmaf(zk, sW[k * N_CLASSES + j * 5 + i], o[i]);
    }

    float m = o[0];
#pragma unroll
    for (int i = 1; i < 5; ++i) m = fmaxf(m, o[i]);
#pragma unroll
    for (int d = 1; d < 8; d <<= 1) m = fmaxf(m, __shfl_xor(m, d, 8));
    float se = 0.f;
#pragma unroll
    for (int i = 0; i < 5; ++i) se += __expf(o[i] - m);
#pragma unroll
    for (int d = 1; d < 8; d <<= 1) se += __shfl_xor(se, d, 8);
    const float lse = m + __logf(se);

    float* orow = out + (size_t)n * N_CLASSES + j * 5;
#pragma unroll
    for (int i = 0; i < 5; ++i) orow[i] = o[i] - lse;
}

extern "C" void kernel_launch(void* const* d_in, const int* in_sizes, int n_in,
                              void* d_out, int out_size, void* d_ws, size_t ws_size,
                              hipStream_t stream) {
    const float* features = (const float*)d_in[0];  // [50000,100]
    const int*   edge_src = (const int*)d_in[1];    // [800000]
    const int*   edge_dst = (const int*)d_in[2];    // [800000]
    const float* edge_val = (const float*)d_in[3];  // [800000]
    const float* W1       = (const float*)d_in[4];  // [100,16]
    const float* W2       = (const float*)d_in[5];  // [16,40]
    float*       out      = (float*)d_out;          // [50000,40]

    char* base = (char*)d_ws;
    const size_t HNB = (size_t)N_NODES * HIDDEN * sizeof(float);       // 3.2 MB
    float* y1     = (float*)(base);
    float* z1     = (float*)(base + HNB);
    int2*  binned = (int2*) (base + 2 * HNB);                          // 6.4 MB
    int2*  sortd  = (int2*) (base + 2 * HNB + (size_t)N_EDGES * 8);    // 12.8 MB
    char*  tail   = base + 2 * HNB + (size_t)N_EDGES * 8
                         + (size_t)NBKT * CAP * 8;
    int*   BTt    = (int*) (tail);                                     // 783*256*4 ≈ 802 KB
    int2*  meta   = (int2*)(tail + (((size_t)(NBKT + 1) * PB * 4 + 255) & ~255ULL));

    // --- build: 2 dispatches, all writes coalesced, zero global atomics ---
    partition_kernel<<<PB, 512, 0, stream>>>(edge_src, edge_dst, edge_val, BTt, binned);
    sort_kernel<<<NBKT, 256, 0, stream>>>(BTt, binned, sortd, meta);

    // --- dense pipeline: 3 dispatches ---
    gemm_xw1<<<(N_NODES + GROWS - 1) / GROWS, 256, 0, stream>>>(features, W1, y1);
    gather_spmm<true><<<(N_NODES + GNODES - 1) / GNODES, 256, 0, stream>>>(meta, sortd, y1, z1);
    gather_out<<<(N_NODES + GNODES - 1) / GNODES, 256, 0, stream>>>(meta, sortd, z1, W2, out);
}

// Round 6
// 125.557 us; speedup vs baseline: 2.5257x; 1.1075x over previous
//
#include <hip/hip_runtime.h>

#define N_NODES   50000
#define N_EDGES   800000
#define IN_DIM    100
#define HIDDEN    16
#define N_CLASSES 40

// Bucketing geometry: bucket = dst >> 6 (64 nodes per bucket)
#define BSHIFT 6
#define NPB    64                        // nodes per bucket
#define NBKT   782                       // ceil(N_NODES / NPB)
#define PB     256                       // partition blocks
#define EPB    3125                      // edges per partition block (256*3125 = 800000)
#define EPT    7                         // max edges held in regs per thread (ceil(3125/512))
#define CAP    2048                      // padded per-bucket capacity (mean 1024, sd 32)
#define GNODES 32                        // nodes per gather_out block (8 lanes/node)
#define GEMMB  782                       // gemm sub-grid: ceil(50000/64)

// K1 LDS union:
//  partition: cnt[782]@0 (pad->3200) | lcur[782]@3200 (pad->6400) | sd[512]@6400
//             | staged int2[3125]@8448 .. 33448
//  gemm:      sX[64*100]@0 .. 25600   | sW[1600]@25600 .. 32000
#define K1_LDS 33456

// ---------------------------------------------------------------------------
// K1: blocks [0,PB) partition the edge list (edges held in REGISTERS between
// count and scatter -> single global read); blocks [PB, PB+GEMMB) compute
// y1 = X @ W1 concurrently (they are independent).
// BTt transposed: BTt[k*PB + b] = start of bucket k's run in block b's region.
// Payload: {src | dst_low6 << 16, val}.
// ---------------------------------------------------------------------------
__global__ __launch_bounds__(512) void build_and_gemm(const int* __restrict__ src,
                                                      const int* __restrict__ dst,
                                                      const float* __restrict__ val,
                                                      const float* __restrict__ X,
                                                      const float* __restrict__ W,
                                                      int* __restrict__ BTt,
                                                      int2* __restrict__ binned,
                                                      float* __restrict__ Y) {
    __shared__ __align__(16) char smem[K1_LDS];
    const int tid = threadIdx.x;

    if (blockIdx.x < PB) {
        // ---------------- partition path ----------------
        int*  cnt    = (int*)smem;
        int*  lcur   = (int*)(smem + 3200);
        int*  sd     = (int*)(smem + 6400);
        int2* staged = (int2*)(smem + 8448);
        const int b = blockIdx.x, e0 = b * EPB;

        for (int k = tid; k < NBKT; k += 512) cnt[k] = 0;
        __syncthreads();

        // single global read: hold edges in registers, count buckets
        int pk[EPT], ps[EPT]; float pv[EPT];
#pragma unroll
        for (int q = 0; q < EPT; ++q) {
            const int i = tid + q * 512;
            if (i < EPB) {
                const int e = e0 + i;
                const int d = dst[e];
                pk[q] = d >> BSHIFT;
                ps[q] = src[e] | ((d & (NPB - 1)) << 16);
                pv[q] = val[e];
                atomicAdd(&cnt[pk[q]], 1);
            } else pk[q] = -1;
        }
        __syncthreads();

        // block-wide exclusive scan over 782 buckets (2 per thread)
        const int k0 = 2 * tid, k1 = 2 * tid + 1;
        const int a  = (k0 < NBKT) ? cnt[k0] : 0;
        const int bb = (k1 < NBKT) ? cnt[k1] : 0;
        const int s  = a + bb;
        sd[tid] = s;
        __syncthreads();
        for (int off = 1; off < 512; off <<= 1) {
            const int u = (tid >= off) ? sd[tid - off] : 0;
            __syncthreads();
            sd[tid] += u;
            __syncthreads();
        }
        const int excl = sd[tid] - s;
        if (k0 < NBKT) { lcur[k0] = excl;     BTt[k0 * PB + b] = excl; }
        if (k1 < NBKT) { lcur[k1] = excl + a; BTt[k1 * PB + b] = excl + a; }
        if (tid == 0)  BTt[NBKT * PB + b] = EPB;
        __syncthreads();

        // scatter from registers into LDS, bucket-grouped
#pragma unroll
        for (int q = 0; q < EPT; ++q) {
            if (pk[q] >= 0) {
                const int pos = atomicAdd(&lcur[pk[q]], 1);
                staged[pos] = make_int2(ps[q], __float_as_int(pv[q]));
            }
        }
        __syncthreads();

        // linear coalesced copy-out
        for (int i = tid; i < EPB; i += 512)
            binned[e0 + i] = staged[i];
    } else {
        // ---------------- gemm path: 64 rows, thread = (row, float2-col) ----
        float* sX = (float*)smem;
        float* sW = (float*)(smem + 25600);
        const int b2   = blockIdx.x - PB;
        const int row0 = b2 * 64;
        const int nrows = min(64, N_NODES - row0);

        const float4* W4 = (const float4*)W;
        float4* sW4 = (float4*)sW;
        for (int i = tid; i < (IN_DIM * HIDDEN) / 4; i += 512) sW4[i] = W4[i];
        const float4* X4 = (const float4*)(X + (size_t)row0 * IN_DIM);
        float4* sX4 = (float4*)sX;
        const int nf4 = nrows * (IN_DIM / 4);
        for (int i = tid; i < nf4; i += 512) sX4[i] = X4[i];
        __syncthreads();

        const int r = tid >> 3, hh = tid & 7;
        if (r >= nrows) return;
        float2 acc = make_float2(0.f, 0.f);
        const float* xr = &sX[r * IN_DIM];
#pragma unroll
        for (int k = 0; k < IN_DIM; ++k) {
            const float xk = xr[k];
            const float2 w = *(const float2*)&sW[k * HIDDEN + hh * 2];
            acc.x = fmaf(xk, w.x, acc.x);
            acc.y = fmaf(xk, w.y, acc.y);
        }
        *(float2*)&Y[(size_t)(row0 + r) * HIDDEN + hh * 2] = acc;
    }
}

// ---------------------------------------------------------------------------
// K2: per-bucket sort ENTIRELY in LDS (single global read of binned) +
// write sorted/meta for K3 + fused gather1: z1 = relu(A @ y1), 4 lanes/node.
// ---------------------------------------------------------------------------
__global__ __launch_bounds__(256) void sort_gather(const int* __restrict__ BTt,
                                                   const int2* __restrict__ binned,
                                                   const float* __restrict__ Xin,
                                                   int2* __restrict__ sorted,
                                                   int2* __restrict__ meta,
                                                   float* __restrict__ Z) {
    __shared__ int2 raw[CAP];          // 16 KB: bucket edges in arrival order
    __shared__ int2 srt[CAP];          // 16 KB: node-sorted
    __shared__ int  cnt[NPB];
    __shared__ int  cur[NPB];
    __shared__ int  wsum[4];
    const int tid = threadIdx.x, k = blockIdx.x;
    const int lane = tid & 63, w = tid >> 6;

    if (tid < NPB) cnt[tid] = 0;

    // coalesced run boundaries; block-scan of 256 run lengths -> LDS offsets
    const int rs = BTt[k * PB + tid];
    const int re = BTt[(k + 1) * PB + tid];
    const int len = re - rs;
    int x = len;
#pragma unroll
    for (int d = 1; d < 64; d <<= 1) {
        const int y = __shfl_up(x, d, 64);
        if (lane >= d) x += y;
    }
    if (lane == 63) wsum[w] = x;
    __syncthreads();
    int add = 0;
    for (int i = 0; i < w; ++i) add += wsum[i];
    const int tot = wsum[0] + wsum[1] + wsum[2] + wsum[3];

    // single global read: stage this bucket's runs into LDS
    int o = add + x - len;
    const int2* rb = binned + (size_t)tid * EPB;
    for (int p = rs; p < re; ++p, ++o) raw[o] = rb[p];
    __syncthreads();

    // node histogram (LDS only)
    for (int i = tid; i < tot; i += 256)
        atomicAdd(&cnt[(raw[i].x >> 16) & (NPB - 1)], 1);
    __syncthreads();

    // wave scan with even-pad (16B-aligned segments for K3's int4 loads)
    if (tid < NPB) {
        const int v  = cnt[tid];
        const int vp = (v + 1) & ~1;
        int xx = vp;
#pragma unroll
        for (int d = 1; d < 64; d <<= 1) {
            const int y = __shfl_up(xx, d, 64);
            if (tid >= d) xx += y;
        }
        const int excl = xx - vp;
        cur[tid] = excl;
        const int node = k * NPB + tid;
        if (node < N_NODES) meta[node] = make_int2(k * CAP + excl, v);
        if (tid == NPB - 1) wsum[0] = xx;     // padded total (wsum free now)
    }
    __syncthreads();
    const int padTot = wsum[0];

    // rank-scatter LDS -> LDS
    for (int i = tid; i < tot; i += 256) {
        const int2 e = raw[i];
        const int pos = atomicAdd(&cur[(e.x >> 16) & (NPB - 1)], 1);
        srt[pos] = make_int2(e.x & 0xFFFF, e.y);
    }
    __syncthreads();

    // coalesced copy-out for K3
    for (int i = tid; i < padTot; i += 256)
        sorted[(size_t)k * CAP + i] = srt[i];

    // fused gather1: 4 lanes per node, float4 of the 16-wide row
    const int g = tid >> 2, q = tid & 3;
    const int node = k * NPB + g;
    if (node >= N_NODES) return;
    const int deg = cnt[g];
    const int beg = cur[g] - deg;      // cur[g] == excl + deg after ranking
    const float4* X4 = (const float4*)Xin;
    float4 acc = make_float4(0.f, 0.f, 0.f, 0.f);
    for (int p = beg; p < beg + deg; ++p) {
        const int2 e = srt[p];
        const float v = __int_as_float(e.y);
        const float4 xv = X4[(size_t)e.x * 4 + q];
        acc.x = fmaf(v, xv.x, acc.x);
        acc.y = fmaf(v, xv.y, acc.y);
        acc.z = fmaf(v, xv.z, acc.z);
        acc.w = fmaf(v, xv.w, acc.w);
    }
    acc.x = fmaxf(acc.x, 0.f); acc.y = fmaxf(acc.y, 0.f);
    acc.z = fmaxf(acc.z, 0.f); acc.w = fmaxf(acc.w, 0.f);
    ((float4*)Z)[(size_t)node * 4 + q] = acc;
}

// ---------------------------------------------------------------------------
// K3: z2 = A @ z1 (8-lane register gather) -> padded LDS transpose ->
// out = log_softmax(z2 @ W2). Lane j owns classes [5j, 5j+5); width-8 shfl.
// ---------------------------------------------------------------------------
__global__ __launch_bounds__(256) void gather_out(const int2* __restrict__ meta,
                                                  const int2* __restrict__ sorted,
                                                  const float* __restrict__ X,
                                                  const float* __restrict__ W2,
                                                  float* __restrict__ out) {
    __shared__ float sW[HIDDEN * N_CLASSES];   // 2.56 KB
    __shared__ float zt[GNODES * 17];          // +1 pad: conflict-free transpose
    const int tid = threadIdx.x;
    for (int i = tid; i < HIDDEN * N_CLASSES; i += 256) sW[i] = W2[i];

    const int g = tid >> 3, j = tid & 7;
    const int n = blockIdx.x * GNODES + g;

    float2 acc = make_float2(0.f, 0.f);
    if (n < N_NODES) {
        const int2 md = meta[n];
        const int beg = md.x, end = md.x + md.y;
        const float2* X2 = (const float2*)X;
        int p = beg;
        for (; p + 4 <= end; p += 4) {
            const int4 ea = *(const int4*)&sorted[p];
            const int4 eb = *(const int4*)&sorted[p + 2];
            const float2 x0 = X2[(size_t)ea.x * 8 + j];
            const float2 x1 = X2[(size_t)ea.z * 8 + j];
            const float2 x2 = X2[(size_t)eb.x * 8 + j];
            const float2 x3 = X2[(size_t)eb.z * 8 + j];
            const float v0 = __int_as_float(ea.y), v1 = __int_as_float(ea.w);
            const float v2 = __int_as_float(eb.y), v3 = __int_as_float(eb.w);
            acc.x = fmaf(v0, x0.x, acc.x); acc.y = fmaf(v0, x0.y, acc.y);
            acc.x = fmaf(v1, x1.x, acc.x); acc.y = fmaf(v1, x1.y, acc.y);
            acc.x = fmaf(v2, x2.x, acc.x); acc.y = fmaf(v2, x2.y, acc.y);
            acc.x = fmaf(v3, x3.x, acc.x); acc.y = fmaf(v3, x3.y, acc.y);
        }
        for (; p < end; ++p) {
            const int2 e = sorted[p];
            const float2 xv = X2[(size_t)e.x * 8 + j];
            const float v = __int_as_float(e.y);
            acc.x = fmaf(v, xv.x, acc.x); acc.y = fmaf(v, xv.y, acc.y);
        }
    }
    zt[g * 17 + j * 2]     = acc.x;
    zt[g * 17 + j * 2 + 1] = acc.y;
    __syncthreads();
    if (n >= N_NODES) return;

    float z[HIDDEN];
#pragma unroll
    for (int k = 0; k < HIDDEN; ++k) z[k] = zt[g * 17 + k];

    float o[5];
#pragma unroll
    for (int i = 0; i < 5; ++i) o[i] = 0.f;
#pragma unroll
    for (int k = 0; k < HIDDEN; ++k) {
        const float zk = z[k];
#pragma unroll
        for (int i = 0; i < 5; ++i)
            o[i] = fmaf(zk, sW[k * N_CLASSES + j * 5 + i], o[i]);
    }

    float m = o[0];
#pragma unroll
    for (int i = 1; i < 5; ++i) m = fmaxf(m, o[i]);
#pragma unroll
    for (int d = 1; d < 8; d <<= 1) m = fmaxf(m, __shfl_xor(m, d, 8));
    float se = 0.f;
#pragma unroll
    for (int i = 0; i < 5; ++i) se += __expf(o[i] - m);
#pragma unroll
    for (int d = 1; d < 8; d <<= 1) se += __shfl_xor(se, d, 8);
    const float lse = m + __logf(se);

    float* orow = out + (size_t)n * N_CLASSES + j * 5;
#pragma unroll
    for (int i = 0; i < 5; ++i) orow[i] = o[i] - lse;
}

extern "C" void kernel_launch(void* const* d_in, const int* in_sizes, int n_in,
                              void* d_out, int out_size, void* d_ws, size_t ws_size,
                              hipStream_t stream) {
    const float* features = (const float*)d_in[0];  // [50000,100]
    const int*   edge_src = (const int*)d_in[1];    // [800000]
    const int*   edge_dst = (const int*)d_in[2];    // [800000]
    const float* edge_val = (const float*)d_in[3];  // [800000]
    const float* W1       = (const float*)d_in[4];  // [100,16]
    const float* W2       = (const float*)d_in[5];  // [16,40]
    float*       out      = (float*)d_out;          // [50000,40]

    char* base = (char*)d_ws;
    const size_t HNB = (size_t)N_NODES * HIDDEN * sizeof(float);       // 3.2 MB
    float* y1     = (float*)(base);
    float* z1     = (float*)(base + HNB);
    int2*  binned = (int2*) (base + 2 * HNB);                          // 6.4 MB
    int2*  sortd  = (int2*) (base + 2 * HNB + (size_t)N_EDGES * 8);    // 12.8 MB
    char*  tail   = base + 2 * HNB + (size_t)N_EDGES * 8
                         + (size_t)NBKT * CAP * 8;
    int*   BTt    = (int*) (tail);                                     // 783*256*4 ≈ 802 KB
    int2*  meta   = (int2*)(tail + (((size_t)(NBKT + 1) * PB * 4 + 255) & ~255ULL));

    // K1: partition (blocks 0..255) || gemm y1 = X@W1 (blocks 256..1037)
    build_and_gemm<<<PB + GEMMB, 512, 0, stream>>>(edge_src, edge_dst, edge_val,
                                                   features, W1, BTt, binned, y1);
    // K2: per-bucket LDS sort -> sorted/meta + fused z1 = relu(A @ y1)
    sort_gather<<<NBKT, 256, 0, stream>>>(BTt, binned, y1, sortd, meta, z1);
    // K3: z2 = A @ z1 fused with log_softmax(z2 @ W2)
    gather_out<<<(N_NODES + GNODES - 1) / GNODES, 256, 0, stream>>>(meta, sortd, z1, W2, out);
}